// Round 5
// baseline (143.184 us; speedup 1.0000x reference)
//
#include <hip/hip_runtime.h>

// Problem geometry (fixed by setup_inputs): B=8, C=3, H=512, W=1024
#define HW_C   524288        // 512*1024 (power of two: p>>19 = batch, p&(HW-1) = hw)
#define NPIX   4194304       // 8*HW_C
#define NG     (NPIX / 4)    // float4 groups
#define GRID   2048
#define BLK    256
// NG == 2 * GRID * BLK exactly -> each thread owns exactly 2 float4 groups

// hardware transcendentals: v_log_f32 (log2), v_exp_f32 (2^x)
__device__ __forceinline__ float fast_pow04(float x) {
    // x in [0,1]; x==0 -> log2=-inf -> exp2=0 (matches pow(0,0.4))
    return __builtin_amdgcn_exp2f(0.4f * __builtin_amdgcn_logf(x));
}

// non-temporal vector loads: read-once streams must not thrash L2/L3
// (nt = replacement hint on gfx950; still hits cache if line is present)
typedef float vfloat4 __attribute__((ext_vector_type(4)));
typedef int   vint4   __attribute__((ext_vector_type(4)));
__device__ __forceinline__ float4 ntload4(const float* p) {
    vfloat4 v = __builtin_nontemporal_load((const vfloat4*)p);
    return make_float4(v.x, v.y, v.z, v.w);
}
__device__ __forceinline__ int4 ntloadi4(const int* p) {
    vint4 v = __builtin_nontemporal_load((const vint4*)p);
    return make_int4(v.x, v.y, v.z, v.w);
}

__constant__ float c_night[19] = {
    (float)(76.5113984140019/255.0),  (float)(76.23163212875781/255.0),
    (float)(60.90662084364415/255.0), (float)(69.06930071129905/255.0),
    (float)(69.63671393061327/255.0), (float)(73.11413822794262/255.0),
    (float)(140.7827781957324/255.0), (float)(116.29554873008291/255.0),
    (float)(46.23329954488532/255.0), (float)(57.839322341112386/255.0),
    (float)(32.61465346757989/255.0), (float)(57.4385179294615/255.0),
    (float)(62.234896087294814/255.0),(float)(90.90285758569436/255.0),
    (float)(91.99610158117673/255.0), (float)(91.82209397173472/255.0),
    (float)(94.06478985576457/255.0), (float)(74.6924145472464/255.0),
    (float)(69.15034088822232/255.0)
};
__constant__ float c_city[19] = {
    (float)(86.46051320057052/255.0), (float)(79.37014543897092/255.0),
    (float)(95.30679177391578/255.0), (float)(71.11888521745776/255.0),
    (float)(75.57026559270716/255.0), (float)(77.90493757655786/255.0),
    (float)(74.77466800282637/255.0), (float)(88.27701037425895/255.0),
    (float)(57.685269557270146/255.0),(float)(72.71472387765841/255.0),
    (float)(229.9589238353863/255.0), (float)(66.9194012998903/255.0),
    (float)(60.42471796718752/255.0), (float)(76.8407421534007/255.0),
    (float)(74.98657626719087/255.0), (float)(73.56771430328095/255.0),
    (float)(123.92515568872523/255.0),(float)(68.93476495876828/255.0),
    (float)(76.0970460111028/255.0)
};

// -------- Pass 1: illum0 = max3(org) - NIGHT[seg]; store illum+seg8; per-block min/max --------
template<bool STORE>
__global__ __launch_bounds__(BLK, 4) void k_pass1(const float* __restrict__ org,
                                                  const int* __restrict__ seg,
                                                  float* __restrict__ illum,
                                                  uchar4* __restrict__ seg8,
                                                  float2* __restrict__ bmm)
{
    // lane-register table: lane l holds night[l]; lookup = ds_bpermute via __shfl
    const int lane = threadIdx.x & 63;
    const float night_reg = c_night[lane < 19 ? lane : 0];

    const int t  = blockIdx.x * BLK + threadIdx.x;
    const int i0 = t;
    const int i1 = t + GRID * BLK;

    const int p0 = i0 << 2, p1 = i1 << 2;
    const size_t base0 = (size_t)(p0 >> 19) * (3 * HW_C) + (p0 & (HW_C - 1));
    const size_t base1 = (size_t)(p1 >> 19) * (3 * HW_C) + (p1 & (HW_C - 1));

    // issue ALL independent loads up front (8 x 16B per lane in flight); org/seg are
    // read-once in the STORE path -> non-temporal
    const float4 r0 = ntload4(org + base0);
    const float4 g0 = ntload4(org + base0 + HW_C);
    const float4 b0 = ntload4(org + base0 + 2 * HW_C);
    const float4 r1 = ntload4(org + base1);
    const float4 g1 = ntload4(org + base1 + HW_C);
    const float4 b1 = ntload4(org + base1 + 2 * HW_C);
    const int4  s0 = ntloadi4(seg + p0);
    const int4  s1 = ntloadi4(seg + p1);

    float4 il0, il1;
    il0.x = fmaxf(fmaxf(r0.x, g0.x), b0.x) - __shfl(night_reg, s0.x);
    il0.y = fmaxf(fmaxf(r0.y, g0.y), b0.y) - __shfl(night_reg, s0.y);
    il0.z = fmaxf(fmaxf(r0.z, g0.z), b0.z) - __shfl(night_reg, s0.z);
    il0.w = fmaxf(fmaxf(r0.w, g0.w), b0.w) - __shfl(night_reg, s0.w);
    il1.x = fmaxf(fmaxf(r1.x, g1.x), b1.x) - __shfl(night_reg, s1.x);
    il1.y = fmaxf(fmaxf(r1.y, g1.y), b1.y) - __shfl(night_reg, s1.y);
    il1.z = fmaxf(fmaxf(r1.z, g1.z), b1.z) - __shfl(night_reg, s1.z);
    il1.w = fmaxf(fmaxf(r1.w, g1.w), b1.w) - __shfl(night_reg, s1.w);

    if (STORE) {
        // keep these on the cached path: pass2 re-reads them (21 MB round-trip)
        *(float4*)(illum + p0) = il0;
        *(float4*)(illum + p1) = il1;
        seg8[i0] = make_uchar4((unsigned char)s0.x, (unsigned char)s0.y,
                               (unsigned char)s0.z, (unsigned char)s0.w);
        seg8[i1] = make_uchar4((unsigned char)s1.x, (unsigned char)s1.y,
                               (unsigned char)s1.z, (unsigned char)s1.w);
    }

    float lmin = fminf(fminf(fminf(il0.x, il0.y), fminf(il0.z, il0.w)),
                       fminf(fminf(il1.x, il1.y), fminf(il1.z, il1.w)));
    float lmax = fmaxf(fmaxf(fmaxf(il0.x, il0.y), fmaxf(il0.z, il0.w)),
                       fmaxf(fmaxf(il1.x, il1.y), fmaxf(il1.z, il1.w)));

    for (int off = 32; off > 0; off >>= 1) {
        lmin = fminf(lmin, __shfl_down(lmin, off));
        lmax = fmaxf(lmax, __shfl_down(lmax, off));
    }
    __shared__ float smin[BLK / 64], smax[BLK / 64];
    const int wave = threadIdx.x >> 6;
    if ((threadIdx.x & 63) == 0) { smin[wave] = lmin; smax[wave] = lmax; }
    __syncthreads();
    if (threadIdx.x == 0) {
        float m = smin[0], M = smax[0];
        #pragma unroll
        for (int w = 1; w < BLK / 64; ++w) { m = fminf(m, smin[w]); M = fmaxf(M, smax[w]); }
        bmm[blockIdx.x] = make_float2(m, M);   // plain store: no atomics, no init, no fences
    }
}

// -------- Pass 2: reduce bmm -> (imin,imax); normalize/gamma/+CITY/clip; channel sums --------
template<bool STORE>
__global__ __launch_bounds__(BLK, 4) void k_pass2(const float* __restrict__ refl,
                                                  const float* __restrict__ org,
                                                  const int* __restrict__ seg,
                                                  const float* __restrict__ illum,
                                                  const uchar4* __restrict__ seg8,
                                                  const float2* __restrict__ bmm,
                                                  double* __restrict__ partial)
{
    const int lane = threadIdx.x & 63;
    const float city_reg = c_city[lane < 19 ? lane : 0];

    const int t  = blockIdx.x * BLK + threadIdx.x;
    const int i0 = t;
    const int i1 = t + GRID * BLK;
    const int p0 = i0 << 2, p1 = i1 << 2;
    const size_t base0 = (size_t)(p0 >> 19) * (3 * HW_C) + (p0 & (HW_C - 1));
    const size_t base1 = (size_t)(p1 >> 19) * (3 * HW_C) + (p1 & (HW_C - 1));

    // small bmm loads first (finish early), then the big main loads — all in flight
    float2 mm[8];
    #pragma unroll
    for (int k = 0; k < 8; ++k) mm[k] = bmm[threadIdx.x + k * BLK];

    float4 il0, il1; uchar4 q0, q1;
    float4 o_r0, o_g0, o_b0, o_r1, o_g1, o_b1; int4 sv0, sv1;
    if (STORE) {
        // cached path: written by pass1, hopefully still L2/L3-resident
        il0 = *(const float4*)(illum + p0);
        il1 = *(const float4*)(illum + p1);
        q0 = seg8[i0]; q1 = seg8[i1];
    } else {
        o_r0 = ntload4(org + base0);
        o_g0 = ntload4(org + base0 + HW_C);
        o_b0 = ntload4(org + base0 + 2 * HW_C);
        o_r1 = ntload4(org + base1);
        o_g1 = ntload4(org + base1 + HW_C);
        o_b1 = ntload4(org + base1 + 2 * HW_C);
        sv0 = ntloadi4(seg + p0);
        sv1 = ntloadi4(seg + p1);
    }
    // refl is read-once -> non-temporal
    const float4 rr0 = ntload4(refl + base0);
    const float4 gg0 = ntload4(refl + base0 + HW_C);
    const float4 bb0 = ntload4(refl + base0 + 2 * HW_C);
    const float4 rr1 = ntload4(refl + base1);
    const float4 gg1 = ntload4(refl + base1 + HW_C);
    const float4 bb1 = ntload4(refl + base1 + 2 * HW_C);

    // redundant per-block reduce of the 2048 block min/max (L2-hot, hidden by loads above)
    float lmin = mm[0].x, lmax = mm[0].y;
    #pragma unroll
    for (int k = 1; k < 8; ++k) { lmin = fminf(lmin, mm[k].x); lmax = fmaxf(lmax, mm[k].y); }
    for (int off = 32; off > 0; off >>= 1) {
        lmin = fminf(lmin, __shfl_down(lmin, off));
        lmax = fmaxf(lmax, __shfl_down(lmax, off));
    }
    __shared__ float smin[BLK / 64], smax[BLK / 64];
    __shared__ float s_imin, s_inv;
    const int wave = threadIdx.x >> 6;
    if ((threadIdx.x & 63) == 0) { smin[wave] = lmin; smax[wave] = lmax; }
    __syncthreads();
    if (threadIdx.x == 0) {
        float m = smin[0], M = smax[0];
        #pragma unroll
        for (int w = 1; w < BLK / 64; ++w) { m = fminf(m, smin[w]); M = fmaxf(M, smax[w]); }
        s_imin = m;
        s_inv  = 1.0f / (M - m);
    }
    __syncthreads();
    const float imin = s_imin, inv = s_inv;

    float c00, c01, c02, c03, c10, c11, c12, c13;
    if (STORE) {
        c00 = __shfl(city_reg, (int)q0.x); c01 = __shfl(city_reg, (int)q0.y);
        c02 = __shfl(city_reg, (int)q0.z); c03 = __shfl(city_reg, (int)q0.w);
        c10 = __shfl(city_reg, (int)q1.x); c11 = __shfl(city_reg, (int)q1.y);
        c12 = __shfl(city_reg, (int)q1.z); c13 = __shfl(city_reg, (int)q1.w);
    } else {
        il0.x = fmaxf(fmaxf(o_r0.x, o_g0.x), o_b0.x);
        il0.y = fmaxf(fmaxf(o_r0.y, o_g0.y), o_b0.y);
        il0.z = fmaxf(fmaxf(o_r0.z, o_g0.z), o_b0.z);
        il0.w = fmaxf(fmaxf(o_r0.w, o_g0.w), o_b0.w);
        il1.x = fmaxf(fmaxf(o_r1.x, o_g1.x), o_b1.x);
        il1.y = fmaxf(fmaxf(o_r1.y, o_g1.y), o_b1.y);
        il1.z = fmaxf(fmaxf(o_r1.z, o_g1.z), o_b1.z);
        il1.w = fmaxf(fmaxf(o_r1.w, o_g1.w), o_b1.w);
        const float night_reg2 = c_night[lane < 19 ? lane : 0];
        il0.x -= __shfl(night_reg2, sv0.x); il0.y -= __shfl(night_reg2, sv0.y);
        il0.z -= __shfl(night_reg2, sv0.z); il0.w -= __shfl(night_reg2, sv0.w);
        il1.x -= __shfl(night_reg2, sv1.x); il1.y -= __shfl(night_reg2, sv1.y);
        il1.z -= __shfl(night_reg2, sv1.z); il1.w -= __shfl(night_reg2, sv1.w);
        c00 = __shfl(city_reg, sv0.x); c01 = __shfl(city_reg, sv0.y);
        c02 = __shfl(city_reg, sv0.z); c03 = __shfl(city_reg, sv0.w);
        c10 = __shfl(city_reg, sv1.x); c11 = __shfl(city_reg, sv1.y);
        c12 = __shfl(city_reg, sv1.z); c13 = __shfl(city_reg, sv1.w);
    }

    float sr = 0.f, sg = 0.f, sb = 0.f;   // 8 pixels/thread: fp32 partials are safe
    float x, z;
    x = (il0.x - imin) * inv; z = fminf(fmaxf(fast_pow04(x) + c00, 0.f), 1.f);
    sr += rr0.x * z; sg += gg0.x * z; sb += bb0.x * z;
    x = (il0.y - imin) * inv; z = fminf(fmaxf(fast_pow04(x) + c01, 0.f), 1.f);
    sr += rr0.y * z; sg += gg0.y * z; sb += bb0.y * z;
    x = (il0.z - imin) * inv; z = fminf(fmaxf(fast_pow04(x) + c02, 0.f), 1.f);
    sr += rr0.z * z; sg += gg0.z * z; sb += bb0.z * z;
    x = (il0.w - imin) * inv; z = fminf(fmaxf(fast_pow04(x) + c03, 0.f), 1.f);
    sr += rr0.w * z; sg += gg0.w * z; sb += bb0.w * z;
    x = (il1.x - imin) * inv; z = fminf(fmaxf(fast_pow04(x) + c10, 0.f), 1.f);
    sr += rr1.x * z; sg += gg1.x * z; sb += bb1.x * z;
    x = (il1.y - imin) * inv; z = fminf(fmaxf(fast_pow04(x) + c11, 0.f), 1.f);
    sr += rr1.y * z; sg += gg1.y * z; sb += bb1.y * z;
    x = (il1.z - imin) * inv; z = fminf(fmaxf(fast_pow04(x) + c12, 0.f), 1.f);
    sr += rr1.z * z; sg += gg1.z * z; sb += bb1.z * z;
    x = (il1.w - imin) * inv; z = fminf(fmaxf(fast_pow04(x) + c13, 0.f), 1.f);
    sr += rr1.w * z; sg += gg1.w * z; sb += bb1.w * z;

    // block reduce in double
    double vr = sr, vg = sg, vb = sb;
    for (int off = 32; off > 0; off >>= 1) {
        vr += __shfl_down(vr, off);
        vg += __shfl_down(vg, off);
        vb += __shfl_down(vb, off);
    }
    __shared__ double sh[3][BLK / 64];
    if ((threadIdx.x & 63) == 0) { sh[0][wave] = vr; sh[1][wave] = vg; sh[2][wave] = vb; }
    __syncthreads();
    if (threadIdx.x == 0) {
        double tr = 0, tg = 0, tb = 0;
        #pragma unroll
        for (int w = 0; w < BLK / 64; ++w) { tr += sh[0][w]; tg += sh[1][w]; tb += sh[2][w]; }
        partial[3 * blockIdx.x + 0] = tr;
        partial[3 * blockIdx.x + 1] = tg;
        partial[3 * blockIdx.x + 2] = tb;
    }
}

// -------- Final: one block reduces 2048x3 doubles -> scalar loss --------
__global__ __launch_bounds__(BLK) void k_final(const double* __restrict__ partial,
                                               float* __restrict__ out)
{
    double sr = 0, sg = 0, sb = 0;
    for (int i = threadIdx.x; i < GRID; i += BLK) {
        sr += partial[3 * i + 0];
        sg += partial[3 * i + 1];
        sb += partial[3 * i + 2];
    }
    for (int off = 32; off > 0; off >>= 1) {
        sr += __shfl_down(sr, off);
        sg += __shfl_down(sg, off);
        sb += __shfl_down(sb, off);
    }
    __shared__ double sh[3][BLK / 64];
    const int wave = threadIdx.x >> 6;
    if ((threadIdx.x & 63) == 0) { sh[0][wave] = sr; sh[1][wave] = sg; sh[2][wave] = sb; }
    __syncthreads();
    if (threadIdx.x == 0) {
        double tr = 0, tg = 0, tb = 0;
        #pragma unroll
        for (int w = 0; w < BLK / 64; ++w) { tr += sh[0][w]; tg += sh[1][w]; tb += sh[2][w]; }
        const double n = (double)NPIX;
        const double r = tr / n, g = tg / n, b = tb / n;
        out[0] = (float)((r - g) * (r - g) + (r - b) * (r - b) + (g - b) * (g - b));
    }
}

extern "C" void kernel_launch(void* const* d_in, const int* in_sizes, int n_in,
                              void* d_out, int out_size, void* d_ws, size_t ws_size,
                              hipStream_t stream) {
    const float* refl = (const float*)d_in[0];
    const float* org  = (const float*)d_in[1];
    const int*   seg  = (const int*)d_in[2];
    float* out = (float*)d_out;

    unsigned char* wsb = (unsigned char*)d_ws;
    float2*  bmm     = (float2*)(wsb + 4096);              // @4K   16 KiB
    double*  partial = (double*)(wsb + 24576);             // @24K  48 KiB
    float*   illum   = (float*)(wsb + 131072);             // @128K 16 MiB
    uchar4*  seg8    = (uchar4*)(wsb + 131072 + sizeof(float) * (size_t)NPIX); // 4 MiB
    const size_t needed = 131072 + 5ull * (size_t)NPIX;
    const bool store = (ws_size >= needed);

    if (store) {
        k_pass1<true ><<<GRID, BLK, 0, stream>>>(org, seg, illum, seg8, bmm);
        k_pass2<true ><<<GRID, BLK, 0, stream>>>(refl, org, seg, illum, seg8, bmm, partial);
    } else {
        k_pass1<false><<<GRID, BLK, 0, stream>>>(org, seg, illum, seg8, bmm);
        k_pass2<false><<<GRID, BLK, 0, stream>>>(refl, org, seg, illum, seg8, bmm, partial);
    }
    k_final<<<1, BLK, 0, stream>>>(partial, out);
}

// Round 6
// 138.025 us; speedup vs baseline: 1.0374x; 1.0374x over previous
//
#include <hip/hip_runtime.h>

// Problem geometry (fixed by setup_inputs): B=8, C=3, H=512, W=1024
#define HW_C   524288        // 512*1024 (power of two: p>>19 = batch, p&(HW-1) = hw)
#define NPIX   4194304       // 8*HW_C
#define NG     (NPIX / 4)    // float4 groups
#define GRID   1024
#define BLK    256
#define SLICE  (GRID * BLK)  // 262144; NG == 4*SLICE exactly -> 4 float4 groups per thread

// hardware transcendentals: v_log_f32 (log2), v_exp_f32 (2^x)
__device__ __forceinline__ float fast_pow04(float x) {
    // x in [0,1]; x==0 -> log2=-inf -> exp2=0 (matches pow(0,0.4))
    return __builtin_amdgcn_exp2f(0.4f * __builtin_amdgcn_logf(x));
}

__constant__ float c_night[19] = {
    (float)(76.5113984140019/255.0),  (float)(76.23163212875781/255.0),
    (float)(60.90662084364415/255.0), (float)(69.06930071129905/255.0),
    (float)(69.63671393061327/255.0), (float)(73.11413822794262/255.0),
    (float)(140.7827781957324/255.0), (float)(116.29554873008291/255.0),
    (float)(46.23329954488532/255.0), (float)(57.839322341112386/255.0),
    (float)(32.61465346757989/255.0), (float)(57.4385179294615/255.0),
    (float)(62.234896087294814/255.0),(float)(90.90285758569436/255.0),
    (float)(91.99610158117673/255.0), (float)(91.82209397173472/255.0),
    (float)(94.06478985576457/255.0), (float)(74.6924145472464/255.0),
    (float)(69.15034088822232/255.0)
};
__constant__ float c_city[19] = {
    (float)(86.46051320057052/255.0), (float)(79.37014543897092/255.0),
    (float)(95.30679177391578/255.0), (float)(71.11888521745776/255.0),
    (float)(75.57026559270716/255.0), (float)(77.90493757655786/255.0),
    (float)(74.77466800282637/255.0), (float)(88.27701037425895/255.0),
    (float)(57.685269557270146/255.0),(float)(72.71472387765841/255.0),
    (float)(229.9589238353863/255.0), (float)(66.9194012998903/255.0),
    (float)(60.42471796718752/255.0), (float)(76.8407421534007/255.0),
    (float)(74.98657626719087/255.0), (float)(73.56771430328095/255.0),
    (float)(123.92515568872523/255.0),(float)(68.93476495876828/255.0),
    (float)(76.0970460111028/255.0)
};

// -------- Pass 1: illum0 = max3(org) - NIGHT[seg]; store illum+seg8; per-block min/max --------
template<bool STORE>
__global__ __launch_bounds__(BLK, 4) void k_pass1(const float* __restrict__ org,
                                                  const int* __restrict__ seg,
                                                  float* __restrict__ illum,
                                                  uchar4* __restrict__ seg8,
                                                  float2* __restrict__ bmm)
{
    // lane-register table: lane l holds night[l]; lookup = ds_bpermute via __shfl
    const int lane = threadIdx.x & 63;
    const float night_reg = c_night[lane < 19 ? lane : 0];
    const int t = blockIdx.x * BLK + threadIdx.x;

    float4 R[4], G[4], Bc[4];
    int4   S[4];
    int    P[4];

    // issue ALL independent loads up front (16 x 16B per lane in flight)
    #pragma unroll
    for (int k = 0; k < 4; ++k) {
        const int p = (t + k * SLICE) << 2;
        P[k] = p;
        const size_t base = (size_t)(p >> 19) * (3 * HW_C) + (p & (HW_C - 1));
        R[k]  = *(const float4*)(org + base);
        G[k]  = *(const float4*)(org + base + HW_C);
        Bc[k] = *(const float4*)(org + base + 2 * HW_C);
        S[k]  = *(const int4*)(seg + p);
    }

    float lmin = 1e30f, lmax = -1e30f;
    #pragma unroll
    for (int k = 0; k < 4; ++k) {
        float4 il;
        il.x = fmaxf(fmaxf(R[k].x, G[k].x), Bc[k].x) - __shfl(night_reg, S[k].x);
        il.y = fmaxf(fmaxf(R[k].y, G[k].y), Bc[k].y) - __shfl(night_reg, S[k].y);
        il.z = fmaxf(fmaxf(R[k].z, G[k].z), Bc[k].z) - __shfl(night_reg, S[k].z);
        il.w = fmaxf(fmaxf(R[k].w, G[k].w), Bc[k].w) - __shfl(night_reg, S[k].w);
        if (STORE) {
            *(float4*)(illum + P[k]) = il;   // cached path: pass2 re-reads (L2/L3-hot)
            seg8[P[k] >> 2] = make_uchar4((unsigned char)S[k].x, (unsigned char)S[k].y,
                                          (unsigned char)S[k].z, (unsigned char)S[k].w);
        }
        lmin = fminf(lmin, fminf(fminf(il.x, il.y), fminf(il.z, il.w)));
        lmax = fmaxf(lmax, fmaxf(fmaxf(il.x, il.y), fmaxf(il.z, il.w)));
    }

    // wave butterfly, then tiny LDS block reduce (end of kernel — barrier harmless here)
    #pragma unroll
    for (int m = 1; m < 64; m <<= 1) {
        lmin = fminf(lmin, __shfl_xor(lmin, m));
        lmax = fmaxf(lmax, __shfl_xor(lmax, m));
    }
    __shared__ float smin[BLK / 64], smax[BLK / 64];
    const int wave = threadIdx.x >> 6;
    if ((threadIdx.x & 63) == 0) { smin[wave] = lmin; smax[wave] = lmax; }
    __syncthreads();
    if (threadIdx.x == 0) {
        float m = smin[0], M = smax[0];
        #pragma unroll
        for (int w = 1; w < BLK / 64; ++w) { m = fminf(m, smin[w]); M = fmaxf(M, smax[w]); }
        bmm[blockIdx.x] = make_float2(m, M);   // plain store: no atomics, no init, no fences
    }
}

// -------- Pass 2: per-WAVE redundant bmm reduce (no mid-kernel barrier!);
//          normalize/gamma/+CITY/clip; channel partial sums --------
template<bool STORE>
__global__ __launch_bounds__(BLK, 4) void k_pass2(const float* __restrict__ refl,
                                                  const float* __restrict__ org,
                                                  const int* __restrict__ seg,
                                                  const float* __restrict__ illum,
                                                  const uchar4* __restrict__ seg8,
                                                  const float2* __restrict__ bmm,
                                                  double* __restrict__ partial)
{
    const int lane = threadIdx.x & 63;
    const float city_reg  = c_city[lane < 19 ? lane : 0];
    const float night_reg = c_night[lane < 19 ? lane : 0];
    const int t = blockIdx.x * BLK + threadIdx.x;

    // bmm loads first (finish earliest, L2-hot): lane reads 16 of the 1024 entries
    float2 mm[16];
    #pragma unroll
    for (int k = 0; k < 16; ++k) mm[k] = bmm[lane + k * 64];

    // then ALL big loads in flight (20 x 16B per lane)
    int P[4];
    size_t baseA[4];
    #pragma unroll
    for (int k = 0; k < 4; ++k) {
        const int p = (t + k * SLICE) << 2;
        P[k] = p;
        baseA[k] = (size_t)(p >> 19) * (3 * HW_C) + (p & (HW_C - 1));
    }

    float4 il[4]; uchar4 q[4];
    float4 oR[4], oG[4], oB[4]; int4 sv[4];
    if (STORE) {
        #pragma unroll
        for (int k = 0; k < 4; ++k) {
            il[k] = *(const float4*)(illum + P[k]);
            q[k]  = seg8[P[k] >> 2];
        }
    } else {
        #pragma unroll
        for (int k = 0; k < 4; ++k) {
            oR[k] = *(const float4*)(org + baseA[k]);
            oG[k] = *(const float4*)(org + baseA[k] + HW_C);
            oB[k] = *(const float4*)(org + baseA[k] + 2 * HW_C);
            sv[k] = *(const int4*)(seg + P[k]);
        }
    }
    float4 rr[4], gg[4], bb[4];
    #pragma unroll
    for (int k = 0; k < 4; ++k) {
        rr[k] = *(const float4*)(refl + baseA[k]);
        gg[k] = *(const float4*)(refl + baseA[k] + HW_C);
        bb[k] = *(const float4*)(refl + baseA[k] + 2 * HW_C);
    }

    // per-wave redundant min/max over all 1024 block entries — waits only on the mm loads,
    // big loads stay in flight; NO __syncthreads / vmcnt(0) drain here
    float lmin = mm[0].x, lmax = mm[0].y;
    #pragma unroll
    for (int k = 1; k < 16; ++k) { lmin = fminf(lmin, mm[k].x); lmax = fmaxf(lmax, mm[k].y); }
    #pragma unroll
    for (int m = 1; m < 64; m <<= 1) {
        lmin = fminf(lmin, __shfl_xor(lmin, m));
        lmax = fmaxf(lmax, __shfl_xor(lmax, m));
    }
    const float imin = lmin;
    const float inv  = 1.0f / (lmax - lmin);

    float sr = 0.f, sg = 0.f, sb = 0.f;   // 16 pixels/thread: fp32 partials still safe (<=16.0)
    #pragma unroll
    for (int k = 0; k < 4; ++k) {
        float c0, c1, c2, c3;
        if (STORE) {
            c0 = __shfl(city_reg, (int)q[k].x); c1 = __shfl(city_reg, (int)q[k].y);
            c2 = __shfl(city_reg, (int)q[k].z); c3 = __shfl(city_reg, (int)q[k].w);
        } else {
            il[k].x = fmaxf(fmaxf(oR[k].x, oG[k].x), oB[k].x) - __shfl(night_reg, sv[k].x);
            il[k].y = fmaxf(fmaxf(oR[k].y, oG[k].y), oB[k].y) - __shfl(night_reg, sv[k].y);
            il[k].z = fmaxf(fmaxf(oR[k].z, oG[k].z), oB[k].z) - __shfl(night_reg, sv[k].z);
            il[k].w = fmaxf(fmaxf(oR[k].w, oG[k].w), oB[k].w) - __shfl(night_reg, sv[k].w);
            c0 = __shfl(city_reg, sv[k].x); c1 = __shfl(city_reg, sv[k].y);
            c2 = __shfl(city_reg, sv[k].z); c3 = __shfl(city_reg, sv[k].w);
        }
        float x, z;
        x = (il[k].x - imin) * inv; z = fminf(fmaxf(fast_pow04(x) + c0, 0.f), 1.f);
        sr += rr[k].x * z; sg += gg[k].x * z; sb += bb[k].x * z;
        x = (il[k].y - imin) * inv; z = fminf(fmaxf(fast_pow04(x) + c1, 0.f), 1.f);
        sr += rr[k].y * z; sg += gg[k].y * z; sb += bb[k].y * z;
        x = (il[k].z - imin) * inv; z = fminf(fmaxf(fast_pow04(x) + c2, 0.f), 1.f);
        sr += rr[k].z * z; sg += gg[k].z * z; sb += bb[k].z * z;
        x = (il[k].w - imin) * inv; z = fminf(fmaxf(fast_pow04(x) + c3, 0.f), 1.f);
        sr += rr[k].w * z; sg += gg[k].w * z; sb += bb[k].w * z;
    }

    // block reduce in double (single barrier, end of kernel)
    double vr = sr, vg = sg, vb = sb;
    for (int off = 32; off > 0; off >>= 1) {
        vr += __shfl_down(vr, off);
        vg += __shfl_down(vg, off);
        vb += __shfl_down(vb, off);
    }
    __shared__ double sh[3][BLK / 64];
    const int wave = threadIdx.x >> 6;
    if ((threadIdx.x & 63) == 0) { sh[0][wave] = vr; sh[1][wave] = vg; sh[2][wave] = vb; }
    __syncthreads();
    if (threadIdx.x == 0) {
        double tr = 0, tg = 0, tb = 0;
        #pragma unroll
        for (int w = 0; w < BLK / 64; ++w) { tr += sh[0][w]; tg += sh[1][w]; tb += sh[2][w]; }
        partial[3 * blockIdx.x + 0] = tr;
        partial[3 * blockIdx.x + 1] = tg;
        partial[3 * blockIdx.x + 2] = tb;
    }
}

// -------- Final: one block reduces 1024x3 doubles -> scalar loss --------
__global__ __launch_bounds__(BLK) void k_final(const double* __restrict__ partial,
                                               float* __restrict__ out)
{
    double sr = 0, sg = 0, sb = 0;
    for (int i = threadIdx.x; i < GRID; i += BLK) {
        sr += partial[3 * i + 0];
        sg += partial[3 * i + 1];
        sb += partial[3 * i + 2];
    }
    for (int off = 32; off > 0; off >>= 1) {
        sr += __shfl_down(sr, off);
        sg += __shfl_down(sg, off);
        sb += __shfl_down(sb, off);
    }
    __shared__ double sh[3][BLK / 64];
    const int wave = threadIdx.x >> 6;
    if ((threadIdx.x & 63) == 0) { sh[0][wave] = sr; sh[1][wave] = sg; sh[2][wave] = sb; }
    __syncthreads();
    if (threadIdx.x == 0) {
        double tr = 0, tg = 0, tb = 0;
        #pragma unroll
        for (int w = 0; w < BLK / 64; ++w) { tr += sh[0][w]; tg += sh[1][w]; tb += sh[2][w]; }
        const double n = (double)NPIX;
        const double r = tr / n, g = tg / n, b = tb / n;
        out[0] = (float)((r - g) * (r - g) + (r - b) * (r - b) + (g - b) * (g - b));
    }
}

extern "C" void kernel_launch(void* const* d_in, const int* in_sizes, int n_in,
                              void* d_out, int out_size, void* d_ws, size_t ws_size,
                              hipStream_t stream) {
    const float* refl = (const float*)d_in[0];
    const float* org  = (const float*)d_in[1];
    const int*   seg  = (const int*)d_in[2];
    float* out = (float*)d_out;

    unsigned char* wsb = (unsigned char*)d_ws;
    float2*  bmm     = (float2*)(wsb + 4096);              // @4K    8 KiB
    double*  partial = (double*)(wsb + 24576);             // @24K  24 KiB
    float*   illum   = (float*)(wsb + 131072);             // @128K 16 MiB
    uchar4*  seg8    = (uchar4*)(wsb + 131072 + sizeof(float) * (size_t)NPIX); // 4 MiB
    const size_t needed = 131072 + 5ull * (size_t)NPIX;
    const bool store = (ws_size >= needed);

    if (store) {
        k_pass1<true ><<<GRID, BLK, 0, stream>>>(org, seg, illum, seg8, bmm);
        k_pass2<true ><<<GRID, BLK, 0, stream>>>(refl, org, seg, illum, seg8, bmm, partial);
    } else {
        k_pass1<false><<<GRID, BLK, 0, stream>>>(org, seg, illum, seg8, bmm);
        k_pass2<false><<<GRID, BLK, 0, stream>>>(refl, org, seg, illum, seg8, bmm, partial);
    }
    k_final<<<1, BLK, 0, stream>>>(partial, out);
}